// Round 1
// baseline (1047.380 us; speedup 1.0000x reference)
//
#include <hip/hip_runtime.h>
#include <hip/hip_bf16.h>
#include <cstdint>

#define BDIM 8
#define LDIM 2500
#define HDIM 512
#define YDIM 8921
#define LPAD 2560
#define YPAD 8960
#define NLT 10
#define NYT 70

using f32x4  = __attribute__((ext_vector_type(4))) float;
using bf16x8 = __attribute__((ext_vector_type(8))) short;

__device__ __forceinline__ unsigned short f2bf(float f) {
  union { float f; unsigned u; } c; c.f = f;
  unsigned u = c.u;
  unsigned r = (u + 0x7fffu + ((u >> 16) & 1u)) >> 16;  // RNE
  return (unsigned short)r;
}

// ---- convert x [8,2500,512] f32 -> [8,2560,512] bf16 (pad rows zero) ----
__global__ void cvt_x_kernel(const float* __restrict__ x, unsigned short* __restrict__ xb) {
  long e = ((long)blockIdx.x * 256 + threadIdx.x) * 4;
  int b   = (int)(e / (LPAD * HDIM));
  int rem = (int)(e - (long)b * (LPAD * HDIM));
  int lp = rem >> 9;
  int h  = rem & 511;
  float4 v = {0.f, 0.f, 0.f, 0.f};
  if (lp < LDIM)
    v = *(const float4*)(x + (((long)(b * LDIM + lp)) << 9) + h);
  ushort4 o;
  o.x = f2bf(v.x); o.y = f2bf(v.y); o.z = f2bf(v.z); o.w = f2bf(v.w);
  *(ushort4*)(xb + e) = o;
}

// ---- convert weights [8921,512] f32 -> [8960,512] bf16 (pad rows zero) ----
__global__ void cvt_w_kernel(const float* __restrict__ w, unsigned short* __restrict__ wb) {
  int e = (blockIdx.x * 256 + threadIdx.x) * 4;
  int row = e >> 9;
  int col = e & 511;
  float4 v = {0.f, 0.f, 0.f, 0.f};
  if (row < YDIM)
    v = *(const float4*)(w + ((long)row << 9) + col);
  ushort4 o;
  o.x = f2bf(v.x); o.y = f2bf(v.y); o.z = f2bf(v.z); o.w = f2bf(v.w);
  *(ushort4*)(wb + e) = o;
}

// ---- fused: S=U*x^T, T=F*x^T, online softmax along l, y = sum(P*T)/sum(P)+bias ----
__global__ __launch_bounds__(512, 2) void fused_kernel(
    const unsigned short* __restrict__ xb,
    const unsigned short* __restrict__ ub,
    const unsigned short* __restrict__ fb,
    const float* __restrict__ bias,
    float* __restrict__ out) {
  // LDS: A panel 256x64 bf16 (32KB) | B panel 256x64 bf16 (32KB) | combine 6KB
  __shared__ __align__(16) unsigned char smem[72 * 1024];

  const int yt  = blockIdx.x;
  const int b   = blockIdx.y;
  const int tid = threadIdx.x;
  const int lane = tid & 63;
  const int wave = tid >> 6;
  const int wm = wave >> 2;   // 0..1 : M half (128 rows = 64 y * {S,T})
  const int wn = wave & 3;    // 0..3 : N quarter (64 cols)
  const int r16  = lane & 15;
  const int kgrp = lane >> 4;

  // fragment read offsets (XOR swizzle on byte 4..6 within 128B row)
  const int xor7  = (r16 & 7) << 4;
  const int koff0 = ((kgrp << 4)) ^ xor7;        // kk=0 : k in [0,32)
  const int koff1 = (64 + (kgrp << 4)) ^ xor7;   // kk=1 : k in [32,64)
  const int arow_base = (wm * 128 + r16) * 128;  // + mt*2048
  const int brow_base = (wn * 64 + r16) * 128;   // + nt*2048 (within B panel)

  // staging source constants: thread t loads 16B to LDS byte t*16
  const int srow   = tid >> 3;          // row within a 64-row issue
  const int kb_lin = (tid & 7) << 4;    // linear byte-in-row slot
  const int kelem  = (kb_lin ^ ((srow & 7) << 4)) >> 1;  // pre-swizzled source elem

  const unsigned short* asrc[4];
#pragma unroll
  for (int i = 0; i < 4; ++i) {
    int m = i * 64 + srow;                         // stacked-W row
    int y_local = ((m >> 5) << 4) + (m & 15);      // 16-row U/F interleave
    const unsigned short* Wsrc = ((m >> 4) & 1) ? fb : ub;
    asrc[i] = Wsrc + (size_t)(yt * 128 + y_local) * 512 + kelem;
  }
  const unsigned short* bsrc[4];
#pragma unroll
  for (int i = 0; i < 4; ++i)
    bsrc[i] = xb + (size_t)(b * LPAD + i * 64 + srow) * 512 + kelem;

  unsigned char* ldsA = smem + wave * 1024;
  unsigned char* ldsB = smem + 32768 + wave * 1024;

  float m_run[4][4], es[4][4], op[4][4];
#pragma unroll
  for (int p = 0; p < 4; ++p)
#pragma unroll
    for (int r = 0; r < 4; ++r) { m_run[p][r] = -1e30f; es[p][r] = 0.f; op[p][r] = 0.f; }

  for (int lt = 0; lt < NLT; ++lt) {
    f32x4 acc[8][4];
#pragma unroll
    for (int mt = 0; mt < 8; ++mt)
#pragma unroll
      for (int nt = 0; nt < 4; ++nt) acc[mt][nt] = {0.f, 0.f, 0.f, 0.f};

    const int boff = lt * 256 * 512;

    for (int ks = 0; ks < 8; ++ks) {
      __syncthreads();   // previous K-step's ds_reads done before overwrite
      const int koff = ks * 64;
#pragma unroll
      for (int i = 0; i < 4; ++i)
        __builtin_amdgcn_global_load_lds(
            (const __attribute__((address_space(1))) void*)(asrc[i] + koff),
            (__attribute__((address_space(3))) void*)(ldsA + i * 8192), 16, 0, 0);
#pragma unroll
      for (int i = 0; i < 4; ++i)
        __builtin_amdgcn_global_load_lds(
            (const __attribute__((address_space(1))) void*)(bsrc[i] + boff + koff),
            (__attribute__((address_space(3))) void*)(ldsB + i * 8192), 16, 0, 0);
      __syncthreads();   // compiler drains vmcnt before barrier

#pragma unroll
      for (int kk = 0; kk < 2; ++kk) {
        const int ko = kk ? koff1 : koff0;
        bf16x8 bfr[4];
#pragma unroll
        for (int nt = 0; nt < 4; ++nt)
          bfr[nt] = *(const bf16x8*)(smem + 32768 + brow_base + nt * 2048 + ko);
#pragma unroll
        for (int mt = 0; mt < 8; ++mt) {
          bf16x8 af = *(const bf16x8*)(smem + arow_base + mt * 2048 + ko);
#pragma unroll
          for (int nt = 0; nt < 4; ++nt)
            acc[mt][nt] = __builtin_amdgcn_mfma_f32_16x16x32_bf16(af, bfr[nt], acc[mt][nt], 0, 0, 0);
        }
      }
    }

    // ---- online-softmax epilogue for this l-tile (register-local S/T pairs) ----
    const bool tail = (lt == NLT - 1);
#pragma unroll
    for (int p = 0; p < 4; ++p) {
#pragma unroll
      for (int r = 0; r < 4; ++r) {
        float mt_l = fmaxf(fmaxf(acc[2 * p][0][r], acc[2 * p][1][r]),
                           fmaxf(acc[2 * p][2][r], acc[2 * p][3][r]));
        mt_l = fmaxf(mt_l, __shfl_xor(mt_l, 1));
        mt_l = fmaxf(mt_l, __shfl_xor(mt_l, 2));
        mt_l = fmaxf(mt_l, __shfl_xor(mt_l, 4));
        mt_l = fmaxf(mt_l, __shfl_xor(mt_l, 8));
        float mo = m_run[p][r];
        float mn = fmaxf(mo, mt_l);
        float sc = __expf(mo - mn);
        float e_ = es[p][r] * sc;
        float o_ = op[p][r] * sc;
#pragma unroll
        for (int nt = 0; nt < 4; ++nt) {
          float s = acc[2 * p][nt][r];
          float t = acc[2 * p + 1][nt][r];
          float pv = __expf(s - mn);
          if (tail) {
            int lg = lt * 256 + wn * 64 + nt * 16 + r16;
            if (lg >= LDIM) pv = 0.f;
          }
          e_ += pv;
          o_ += pv * t;
        }
        m_run[p][r] = mn; es[p][r] = e_; op[p][r] = o_;
      }
    }
  }

  // ---- flash-combine across the 4 N-waves ----
  float* comb = (float*)(smem + 65536);
#pragma unroll
  for (int p = 0; p < 4; ++p) {
#pragma unroll
    for (int r = 0; r < 4; ++r) {
      float e_ = es[p][r], o_ = op[p][r];
      e_ += __shfl_xor(e_, 1); o_ += __shfl_xor(o_, 1);
      e_ += __shfl_xor(e_, 2); o_ += __shfl_xor(o_, 2);
      e_ += __shfl_xor(e_, 4); o_ += __shfl_xor(o_, 4);
      e_ += __shfl_xor(e_, 8); o_ += __shfl_xor(o_, 8);
      if (r16 == 0) {
        int y_loc = (wm * 4 + p) * 16 + kgrp * 4 + r;
        float* c = comb + (y_loc * 4 + wn) * 3;
        c[0] = m_run[p][r]; c[1] = e_; c[2] = o_;
      }
    }
  }
  __syncthreads();
  if (tid < 128) {
    float* c = comb + tid * 12;
    float M = fmaxf(fmaxf(c[0], c[3]), fmaxf(c[6], c[9]));
    float E = 0.f, O = 0.f;
#pragma unroll
    for (int w = 0; w < 4; ++w) {
      float sw = __expf(c[w * 3] - M);
      E += sw * c[w * 3 + 1];
      O += sw * c[w * 3 + 2];
    }
    int y_g = yt * 128 + tid;
    if (y_g < YDIM)
      out[b * YDIM + y_g] = O / E + bias[y_g];
  }
}

// ---- BCE-with-logits mean over [B*Y], single block ----
__global__ void loss_kernel(const float* __restrict__ yv, const float* __restrict__ tgt,
                            float* __restrict__ out) {
  __shared__ float red[1024];
  int tid = threadIdx.x;
  float s = 0.f;
  for (int i = tid; i < BDIM * YDIM; i += 1024) {
    float y = yv[i];
    float t = tgt[i];
    s += fmaxf(y, 0.f) - y * t + log1pf(expf(-fabsf(y)));
  }
  red[tid] = s;
  __syncthreads();
  for (int off = 512; off > 0; off >>= 1) {
    if (tid < off) red[tid] += red[tid + off];
    __syncthreads();
  }
  if (tid == 0) out[BDIM * YDIM] = red[0] / (float)(BDIM * YDIM);
}

extern "C" void kernel_launch(void* const* d_in, const int* in_sizes, int n_in,
                              void* d_out, int out_size, void* d_ws, size_t ws_size,
                              hipStream_t stream) {
  const float* x    = (const float*)d_in[0];
  const float* tgt  = (const float*)d_in[1];
  const float* U    = (const float*)d_in[2];
  const float* F    = (const float*)d_in[3];
  const float* bias = (const float*)d_in[4];
  float* out = (float*)d_out;

  unsigned short* xb = (unsigned short*)d_ws;                    // 8*2560*512  = 10,485,760 elems
  unsigned short* ub = xb + (size_t)BDIM * LPAD * HDIM;          // 8960*512    =  4,587,520
  unsigned short* fw = ub + (size_t)YPAD * HDIM;                 // 8960*512

  cvt_x_kernel<<<10240, 256, 0, stream>>>(x, xb);
  cvt_w_kernel<<<4480, 256, 0, stream>>>(U, ub);
  cvt_w_kernel<<<4480, 256, 0, stream>>>(F, fw);
  fused_kernel<<<dim3(NYT, BDIM), 512, 0, stream>>>(xb, ub, fw, bias, out);
  loss_kernel<<<1, 1024, 0, stream>>>(out, tgt, out);
}

// Round 3
// 749.635 us; speedup vs baseline: 1.3972x; 1.3972x over previous
//
#include <hip/hip_runtime.h>
#include <hip/hip_bf16.h>
#include <cstdint>

#define BDIM 8
#define LDIM 2500
#define HDIM 512
#define YDIM 8921
#define LPAD 2560
#define YPAD 8960
#define NLT 10     // l-tiles of 256
#define NYT 140    // y-tiles of 64 (128 stacked S/T rows)
#define KSTEPS 16  // K=512 / BK=32

using f32x4  = __attribute__((ext_vector_type(4))) float;
using bf16x8 = __attribute__((ext_vector_type(8))) short;

__device__ __forceinline__ unsigned short f2bf(float f) {
  union { float f; unsigned u; } c; c.f = f;
  unsigned u = c.u;
  unsigned r = (u + 0x7fffu + ((u >> 16) & 1u)) >> 16;  // RNE
  return (unsigned short)r;
}

// ---- convert x [8,2500,512] f32 -> [8,2560,512] bf16 (pad rows zero) ----
__global__ void cvt_x_kernel(const float* __restrict__ x, unsigned short* __restrict__ xb) {
  int e = (blockIdx.x * 256 + threadIdx.x) * 4;   // elem within one batch's padded slab
  int b = blockIdx.y;
  int lp = e >> 9;
  int h  = e & 511;
  float4 v = {0.f, 0.f, 0.f, 0.f};
  if (lp < LDIM)
    v = *(const float4*)(x + (((size_t)(b * LDIM + lp)) << 9) + h);
  ushort4 o;
  o.x = f2bf(v.x); o.y = f2bf(v.y); o.z = f2bf(v.z); o.w = f2bf(v.w);
  *(ushort4*)(xb + (((size_t)b * LPAD) << 9) + e) = o;
}

// ---- convert weights [8921,512] f32 -> [8960,512] bf16 (pad rows zero) ----
__global__ void cvt_w_kernel(const float* __restrict__ w, unsigned short* __restrict__ wb) {
  int e = (blockIdx.x * 256 + threadIdx.x) * 4;
  int row = e >> 9;
  int col = e & 511;
  float4 v = {0.f, 0.f, 0.f, 0.f};
  if (row < YDIM)
    v = *(const float4*)(w + ((size_t)row << 9) + col);
  ushort4 o;
  o.x = f2bf(v.x); o.y = f2bf(v.y); o.z = f2bf(v.z); o.w = f2bf(v.w);
  *(ushort4*)(wb + e) = o;
}

// ---- fused: W-persistent-in-LDS, x double-buffered BK=32, online softmax ----
// LDS map: A (W tile) [128 rows][1024B] = 131072   (row m at m*1024, XOR-swizzled)
//          B dbuf: 131072 + buf*16384 + row r (0..255) at r*64 (linear)
//          combine scratch reuses A region after main loop.
__global__ __launch_bounds__(256, 1) void fused_kernel(
    const unsigned short* __restrict__ xb,
    const unsigned short* __restrict__ ub,
    const unsigned short* __restrict__ fb,
    const float* __restrict__ bias,
    float* __restrict__ out) {
  __shared__ __align__(16) unsigned char smem[163840];

  const int wid = blockIdx.x;
  const int b   = wid & 7;        // XCD-pinned batch (8 XCDs, round-robin dispatch)
  const int yt  = wid >> 3;       // 0..139
  const int tid = threadIdx.x;
  const int lane = tid & 63;
  const int wave = tid >> 6;      // 0..3 == l-column quarter
  const int r16  = lane & 15;
  const int kgrp = lane >> 4;
  const int kg16 = kgrp << 4;

  // read-side swizzles
  const int xorA = (r16 & 7) << 4;                 // A rows are 1024B
  const int kB   = kg16 ^ (((r16 >> 1) & 3) << 4); // B rows are 64B

  // ---- stage A (W tile) once: 32 issues x 4KB ----
  {
    const int sl = tid & 63;     // 16B slot within 1KB row
#pragma unroll 4
    for (int i = 0; i < 32; ++i) {
      int m = i * 4 + wave;                       // stacked row 0..127
      const unsigned short* Wsrc = (m & 16) ? fb : ub;
      int yrow = yt * 64 + ((m >> 5) << 4) + (m & 15);
      const unsigned short* src = Wsrc + ((size_t)yrow << 9) + ((sl ^ (m & 7)) << 3);
      __builtin_amdgcn_global_load_lds(
          (const __attribute__((address_space(1))) void*)src,
          (__attribute__((address_space(3))) void*)(smem + i * 4096 + wave * 1024), 16, 0, 0);
    }
  }

  // ---- B staging constants ----
  const int brow  = tid >> 2;                    // row within 64-row issue
  const int bslot = tid & 3;
  const int bswz  = (bslot ^ ((brow >> 1) & 3)) << 3;   // pre-swizzled elem offset
  const unsigned short* pB = xb + (((size_t)b * LPAD) << 9) + bswz;
  size_t rowoff[4];
#pragma unroll
  for (int i = 0; i < 4; ++i) rowoff[i] = ((size_t)(i * 64 + brow)) << 9;

  // prologue: stage B(lt=0, ks=0) into buf0
#pragma unroll
  for (int i = 0; i < 4; ++i)
    __builtin_amdgcn_global_load_lds(
        (const __attribute__((address_space(1))) void*)(pB + rowoff[i]),
        (__attribute__((address_space(3))) void*)(smem + 131072 + i * 4096 + wave * 1024), 16, 0, 0);
  __syncthreads();   // drains A + first B

  float m_run[4][4], es[4][4], op[4][4];
#pragma unroll
  for (int p = 0; p < 4; ++p)
#pragma unroll
    for (int r = 0; r < 4; ++r) { m_run[p][r] = -1e30f; es[p][r] = 0.f; op[p][r] = 0.f; }

  int cur = 0;
  for (int lt = 0; lt < NLT; ++lt) {
    f32x4 acc[8][4];
#pragma unroll
    for (int mt = 0; mt < 8; ++mt)
#pragma unroll
      for (int nt = 0; nt < 4; ++nt) acc[mt][nt] = {0.f, 0.f, 0.f, 0.f};

#pragma unroll 2
    for (int ks = 0; ks < KSTEPS; ++ks) {
      // ---- stage next B step into buf[cur^1] (overlaps with MFMA below) ----
      int nlt = lt, nks = ks + 1;
      if (nks == KSTEPS) { nks = 0; nlt = (lt + 1 < NLT) ? lt + 1 : 0; }
      const unsigned short* bs = pB + (((size_t)nlt) << 17) + (nks << 5);
      unsigned char* bd = smem + 131072 + (cur ^ 1) * 16384 + wave * 1024;
#pragma unroll
      for (int i = 0; i < 4; ++i)
        __builtin_amdgcn_global_load_lds(
            (const __attribute__((address_space(1))) void*)(bs + rowoff[i]),
            (__attribute__((address_space(3))) void*)(bd + i * 4096), 16, 0, 0);

      // ---- fragments + MFMA on buf[cur] ----
      const int kA = ((ks << 6) + kg16) ^ xorA;
      const unsigned char* Bc = smem + 131072 + cur * 16384 + wave * 4096;  // wave's l-quarter
      bf16x8 bfr[4];
#pragma unroll
      for (int nt = 0; nt < 4; ++nt)
        bfr[nt] = *(const bf16x8*)(Bc + nt * 1024 + r16 * 64 + kB);
#pragma unroll
      for (int mt = 0; mt < 8; ++mt) {
        bf16x8 af = *(const bf16x8*)(smem + mt * 16384 + r16 * 1024 + kA);
#pragma unroll
        for (int nt = 0; nt < 4; ++nt)
          acc[mt][nt] = __builtin_amdgcn_mfma_f32_16x16x32_bf16(af, bfr[nt], acc[mt][nt], 0, 0, 0);
      }
      __syncthreads();   // drains next-B loads + all ds_reads of buf[cur]
      cur ^= 1;
    }

    // ---- online-softmax epilogue for this l-tile (register-local S/T) ----
    const bool tail = (lt == NLT - 1);
#pragma unroll
    for (int p = 0; p < 4; ++p) {
#pragma unroll
      for (int r = 0; r < 4; ++r) {
        float mt_l = fmaxf(fmaxf(acc[2 * p][0][r], acc[2 * p][1][r]),
                           fmaxf(acc[2 * p][2][r], acc[2 * p][3][r]));
        mt_l = fmaxf(mt_l, __shfl_xor(mt_l, 1));
        mt_l = fmaxf(mt_l, __shfl_xor(mt_l, 2));
        mt_l = fmaxf(mt_l, __shfl_xor(mt_l, 4));
        mt_l = fmaxf(mt_l, __shfl_xor(mt_l, 8));
        float mo = m_run[p][r];
        float mn = fmaxf(mo, mt_l);
        float sc = __expf(mo - mn);
        float e_ = es[p][r] * sc;
        float o_ = op[p][r] * sc;
#pragma unroll
        for (int nt = 0; nt < 4; ++nt) {
          float s = acc[2 * p][nt][r];
          float t = acc[2 * p + 1][nt][r];
          float pv = __expf(s - mn);
          if (tail) {
            int lg = lt * 256 + wave * 64 + nt * 16 + r16;
            if (lg >= LDIM) pv = 0.f;
          }
          e_ += pv;
          o_ += pv * t;
        }
        m_run[p][r] = mn; es[p][r] = e_; op[p][r] = o_;
      }
    }
  }

  // ---- flash-combine across the 4 l-waves (reuse A region as scratch) ----
  float* comb = (float*)smem;
#pragma unroll
  for (int p = 0; p < 4; ++p) {
#pragma unroll
    for (int r = 0; r < 4; ++r) {
      float e_ = es[p][r], o_ = op[p][r];
      e_ += __shfl_xor(e_, 1); o_ += __shfl_xor(o_, 1);
      e_ += __shfl_xor(e_, 2); o_ += __shfl_xor(o_, 2);
      e_ += __shfl_xor(e_, 4); o_ += __shfl_xor(o_, 4);
      e_ += __shfl_xor(e_, 8); o_ += __shfl_xor(o_, 8);
      if (r16 == 0) {
        int y_loc = p * 16 + kgrp * 4 + r;
        float* c = comb + (y_loc * 4 + wave) * 3;
        c[0] = m_run[p][r]; c[1] = e_; c[2] = o_;
      }
    }
  }
  __syncthreads();
  if (tid < 64) {
    float* c = comb + tid * 12;
    float M = fmaxf(fmaxf(c[0], c[3]), fmaxf(c[6], c[9]));
    float E = 0.f, O = 0.f;
#pragma unroll
    for (int w = 0; w < 4; ++w) {
      float sw = __expf(c[w * 3] - M);
      E += sw * c[w * 3 + 1];
      O += sw * c[w * 3 + 2];
    }
    int y_g = yt * 64 + tid;
    if (y_g < YDIM)
      out[b * YDIM + y_g] = O / E + bias[y_g];
  }
}

// ---- BCE-with-logits: 70-block partial, then final reduce ----
__global__ void loss_part(const float* __restrict__ yv, const float* __restrict__ tgt,
                          float* __restrict__ part) {
  __shared__ float red[256];
  int tid = threadIdx.x;
  int base = blockIdx.x * 1024;
  float s = 0.f;
#pragma unroll
  for (int j = 0; j < 4; ++j) {
    int i = base + j * 256 + tid;
    if (i < BDIM * YDIM) {
      float y = yv[i];
      float t = tgt[i];
      s += fmaxf(y, 0.f) - y * t + log1pf(expf(-fabsf(y)));
    }
  }
  red[tid] = s;
  __syncthreads();
  for (int off = 128; off > 0; off >>= 1) {
    if (tid < off) red[tid] += red[tid + off];
    __syncthreads();
  }
  if (tid == 0) part[blockIdx.x] = red[0];
}

__global__ void loss_final(const float* __restrict__ part, float* __restrict__ out) {
  __shared__ float red[128];
  int tid = threadIdx.x;
  red[tid] = (tid < 70) ? part[tid] : 0.f;
  __syncthreads();
  for (int off = 64; off > 0; off >>= 1) {
    if (tid < off) red[tid] += red[tid + off];
    __syncthreads();
  }
  if (tid == 0) out[BDIM * YDIM] = red[0] / (float)(BDIM * YDIM);
}

extern "C" void kernel_launch(void* const* d_in, const int* in_sizes, int n_in,
                              void* d_out, int out_size, void* d_ws, size_t ws_size,
                              hipStream_t stream) {
  const float* x    = (const float*)d_in[0];
  const float* tgt  = (const float*)d_in[1];
  const float* U    = (const float*)d_in[2];
  const float* F    = (const float*)d_in[3];
  const float* bias = (const float*)d_in[4];
  float* out = (float*)d_out;

  unsigned short* xb = (unsigned short*)d_ws;                    // 8*2560*512
  unsigned short* ub = xb + (size_t)BDIM * LPAD * HDIM;          // 8960*512
  unsigned short* fw = ub + (size_t)YPAD * HDIM;                 // 8960*512
  float* part = (float*)(fw + (size_t)YPAD * HDIM);              // 70 floats

  cvt_x_kernel<<<dim3(1280, BDIM), 256, 0, stream>>>(x, xb);
  cvt_w_kernel<<<4480, 256, 0, stream>>>(U, ub);
  cvt_w_kernel<<<4480, 256, 0, stream>>>(F, fw);
  fused_kernel<<<NYT * BDIM, 256, 0, stream>>>(xb, ub, fw, bias, out);
  loss_part<<<70, 256, 0, stream>>>(out, tgt, part);
  loss_final<<<1, 128, 0, stream>>>(part, out);
}

// Round 4
// 571.786 us; speedup vs baseline: 1.8318x; 1.3110x over previous
//
#include <hip/hip_runtime.h>
#include <hip/hip_bf16.h>
#include <cstdint>

#define BDIM 8
#define LDIM 2500
#define HDIM 512
#define YDIM 8921
#define LPAD 2560
#define YPAD 8960
#define NLT 10     // l-tiles of 256
#define NYT 140    // y-tiles of 64 (128 stacked S/T rows)
#define KSTEPS 16  // K=512 / BK=32

using f32x4  = __attribute__((ext_vector_type(4))) float;
using bf16x8 = __attribute__((ext_vector_type(8))) short;

__device__ __forceinline__ unsigned short f2bf(float f) {
  union { float f; unsigned u; } c; c.f = f;
  unsigned u = c.u;
  unsigned r = (u + 0x7fffu + ((u >> 16) & 1u)) >> 16;  // RNE
  return (unsigned short)r;
}

// ---- convert x [8,2500,512] f32 -> [8,2560,512] bf16 (pad rows zero) ----
__global__ void cvt_x_kernel(const float* __restrict__ x, unsigned short* __restrict__ xb) {
  int e = (blockIdx.x * 256 + threadIdx.x) * 4;   // elem within one batch's padded slab
  int b = blockIdx.y;
  int lp = e >> 9;
  int h  = e & 511;
  float4 v = {0.f, 0.f, 0.f, 0.f};
  if (lp < LDIM)
    v = *(const float4*)(x + (((size_t)(b * LDIM + lp)) << 9) + h);
  ushort4 o;
  o.x = f2bf(v.x); o.y = f2bf(v.y); o.z = f2bf(v.z); o.w = f2bf(v.w);
  *(ushort4*)(xb + (((size_t)b * LPAD) << 9) + e) = o;
}

// ---- convert weights [8921,512] f32 -> [8960,512] bf16 (pad rows zero) ----
__global__ void cvt_w_kernel(const float* __restrict__ w, unsigned short* __restrict__ wb) {
  int e = (blockIdx.x * 256 + threadIdx.x) * 4;
  int row = e >> 9;
  int col = e & 511;
  float4 v = {0.f, 0.f, 0.f, 0.f};
  if (row < YDIM)
    v = *(const float4*)(w + ((size_t)row << 9) + col);
  ushort4 o;
  o.x = f2bf(v.x); o.y = f2bf(v.y); o.z = f2bf(v.z); o.w = f2bf(v.w);
  *(ushort4*)(wb + e) = o;
}

// ---- fused: W-persistent-in-LDS, x double-buffered BK=32, online softmax ----
// 512 threads = 8 waves as 2M x 4N, wave-tile 64x64, acc[4][4].
// LDS map: A (W tile) [128 rows][1024B] = 131072   (row m at m*1024, XOR-swizzled)
//          B dbuf: 131072 + buf*16384 + row r (0..255) at r*64 (linear, XOR within row)
//          combine scratch reuses A region after main loop.
__global__ __launch_bounds__(512, 2) void fused_kernel(
    const unsigned short* __restrict__ xb,
    const unsigned short* __restrict__ ub,
    const unsigned short* __restrict__ fb,
    const float* __restrict__ bias,
    float* __restrict__ out) {
  __shared__ __align__(16) unsigned char smem[163840];

  const int wid = blockIdx.x;
  const int b   = wid & 7;        // XCD-pinned batch (8 XCDs, round-robin dispatch)
  const int yt  = wid >> 3;       // 0..139
  const int tid = threadIdx.x;
  const int lane = tid & 63;
  const int wave = tid >> 6;      // 0..7
  const int wm = wave >> 2;       // 0..1 : M half (64 stacked rows)
  const int wn = wave & 3;        // 0..3 : l-column quarter
  const int r16  = lane & 15;
  const int kgrp = lane >> 4;
  const int kg16 = kgrp << 4;

  // read-side swizzles
  const int xorA = (r16 & 7) << 4;                 // A rows are 1024B
  const int kB   = kg16 ^ (((r16 >> 1) & 3) << 4); // B rows are 64B

  // ---- stage A (W tile) once: 16 issues per wave, row m = i*8 + wave ----
  {
#pragma unroll 4
    for (int i = 0; i < 16; ++i) {
      int m = i * 8 + wave;                       // stacked row 0..127
      const unsigned short* Wsrc = (m & 16) ? fb : ub;
      int yrow = yt * 64 + ((m >> 5) << 4) + (m & 15);
      const unsigned short* src = Wsrc + ((size_t)yrow << 9) + ((lane ^ (m & 7)) << 3);
      __builtin_amdgcn_global_load_lds(
          (const __attribute__((address_space(1))) void*)src,
          (__attribute__((address_space(3))) void*)(smem + m * 1024), 16, 0, 0);
    }
  }

  // ---- B staging constants: per ks, wave stages chunks wave*2 and wave*2+1 ----
  // chunk c covers rows [c*16, c*16+16); lane -> row c*16 + (lane>>2), slot lane&3.
  const int brow0 = wave * 32 + (lane >> 2);            // row for chunk0 = wave*2
  const int bswz  = ((lane & 3) ^ ((brow0 >> 1) & 3)) << 3;  // same for brow0+16
  const unsigned short* pB = xb + (((size_t)b * LPAD) << 9) + bswz;
  const size_t rowoff0 = ((size_t)brow0) << 9;
  const size_t rowoff1 = ((size_t)(brow0 + 16)) << 9;
  unsigned char* bdst0 = smem + 131072 + wave * 2048;   // chunk (wave*2)   * 1024
  unsigned char* bdst1 = bdst0 + 1024;                  // chunk (wave*2+1) * 1024

  // prologue: stage B(lt=0, ks=0) into buf0
  __builtin_amdgcn_global_load_lds(
      (const __attribute__((address_space(1))) void*)(pB + rowoff0),
      (__attribute__((address_space(3))) void*)bdst0, 16, 0, 0);
  __builtin_amdgcn_global_load_lds(
      (const __attribute__((address_space(1))) void*)(pB + rowoff1),
      (__attribute__((address_space(3))) void*)bdst1, 16, 0, 0);
  __syncthreads();   // drains A + first B

  float m_run[2][4], es[2][4], op[2][4];
#pragma unroll
  for (int p = 0; p < 2; ++p)
#pragma unroll
    for (int r = 0; r < 4; ++r) { m_run[p][r] = -1e30f; es[p][r] = 0.f; op[p][r] = 0.f; }

  int cur = 0;
  for (int lt = 0; lt < NLT; ++lt) {
    f32x4 acc[4][4];
#pragma unroll
    for (int mt = 0; mt < 4; ++mt)
#pragma unroll
      for (int nt = 0; nt < 4; ++nt) acc[mt][nt] = {0.f, 0.f, 0.f, 0.f};

#pragma unroll 2
    for (int ks = 0; ks < KSTEPS; ++ks) {
      // ---- stage next B step into buf[cur^1] (overlaps with MFMA below) ----
      int nlt = lt, nks = ks + 1;
      if (nks == KSTEPS) { nks = 0; nlt = (lt + 1 < NLT) ? lt + 1 : 0; }
      const unsigned short* bs = pB + (((size_t)nlt) << 17) + (nks << 5);
      unsigned char* bd = smem + 131072 + (cur ^ 1) * 16384 + wave * 2048;
      __builtin_amdgcn_global_load_lds(
          (const __attribute__((address_space(1))) void*)(bs + rowoff0),
          (__attribute__((address_space(3))) void*)bd, 16, 0, 0);
      __builtin_amdgcn_global_load_lds(
          (const __attribute__((address_space(1))) void*)(bs + rowoff1),
          (__attribute__((address_space(3))) void*)(bd + 1024), 16, 0, 0);

      // ---- fragments + MFMA on buf[cur] ----
      const int kA = ((ks << 6) + kg16) ^ xorA;
      const unsigned char* Bc = smem + 131072 + cur * 16384 + wn * 4096;  // wave's l-quarter
      bf16x8 bfr[4];
#pragma unroll
      for (int nt = 0; nt < 4; ++nt)
        bfr[nt] = *(const bf16x8*)(Bc + nt * 1024 + r16 * 64 + kB);
#pragma unroll
      for (int mt = 0; mt < 4; ++mt) {
        bf16x8 af = *(const bf16x8*)(smem + wm * 65536 + mt * 16384 + r16 * 1024 + kA);
#pragma unroll
        for (int nt = 0; nt < 4; ++nt)
          acc[mt][nt] = __builtin_amdgcn_mfma_f32_16x16x32_bf16(af, bfr[nt], acc[mt][nt], 0, 0, 0);
      }
      __syncthreads();   // drains next-B loads + all ds_reads of buf[cur]
      cur ^= 1;
    }

    // ---- online-softmax epilogue for this l-tile (register-local S/T) ----
    // mt even = S, mt odd = T; pair p = mt>>1; y-group = wm*2 + p.
    const bool tail = (lt == NLT - 1);
#pragma unroll
    for (int p = 0; p < 2; ++p) {
#pragma unroll
      for (int r = 0; r < 4; ++r) {
        float mt_l = fmaxf(fmaxf(acc[2 * p][0][r], acc[2 * p][1][r]),
                           fmaxf(acc[2 * p][2][r], acc[2 * p][3][r]));
        mt_l = fmaxf(mt_l, __shfl_xor(mt_l, 1));
        mt_l = fmaxf(mt_l, __shfl_xor(mt_l, 2));
        mt_l = fmaxf(mt_l, __shfl_xor(mt_l, 4));
        mt_l = fmaxf(mt_l, __shfl_xor(mt_l, 8));
        float mo = m_run[p][r];
        float mn = fmaxf(mo, mt_l);
        float sc = __expf(mo - mn);
        float e_ = es[p][r] * sc;
        float o_ = op[p][r] * sc;
#pragma unroll
        for (int nt = 0; nt < 4; ++nt) {
          float s = acc[2 * p][nt][r];
          float t = acc[2 * p + 1][nt][r];
          float pv = __expf(s - mn);
          if (tail) {
            int lg = lt * 256 + wn * 64 + nt * 16 + r16;
            if (lg >= LDIM) pv = 0.f;
          }
          e_ += pv;
          o_ += pv * t;
        }
        m_run[p][r] = mn; es[p][r] = e_; op[p][r] = o_;
      }
    }
  }

  // ---- flash-combine across the 4 l-waves (reuse A region as scratch) ----
  float* comb = (float*)smem;
#pragma unroll
  for (int p = 0; p < 2; ++p) {
#pragma unroll
    for (int r = 0; r < 4; ++r) {
      float e_ = es[p][r], o_ = op[p][r];
      e_ += __shfl_xor(e_, 1); o_ += __shfl_xor(o_, 1);
      e_ += __shfl_xor(e_, 2); o_ += __shfl_xor(o_, 2);
      e_ += __shfl_xor(e_, 4); o_ += __shfl_xor(o_, 4);
      e_ += __shfl_xor(e_, 8); o_ += __shfl_xor(o_, 8);
      if (r16 == 0) {
        int y_loc = (wm * 2 + p) * 16 + kgrp * 4 + r;
        float* c = comb + (y_loc * 4 + wn) * 3;
        c[0] = m_run[p][r]; c[1] = e_; c[2] = o_;
      }
    }
  }
  __syncthreads();
  if (tid < 64) {
    float* c = comb + tid * 12;
    float M = fmaxf(fmaxf(c[0], c[3]), fmaxf(c[6], c[9]));
    float E = 0.f, O = 0.f;
#pragma unroll
    for (int w = 0; w < 4; ++w) {
      float sw = __expf(c[w * 3] - M);
      E += sw * c[w * 3 + 1];
      O += sw * c[w * 3 + 2];
    }
    int y_g = yt * 64 + tid;
    if (y_g < YDIM)
      out[b * YDIM + y_g] = O / E + bias[y_g];
  }
}

// ---- BCE-with-logits: 70-block partial, then final reduce ----
__global__ void loss_part(const float* __restrict__ yv, const float* __restrict__ tgt,
                          float* __restrict__ part) {
  __shared__ float red[256];
  int tid = threadIdx.x;
  int base = blockIdx.x * 1024;
  float s = 0.f;
#pragma unroll
  for (int j = 0; j < 4; ++j) {
    int i = base + j * 256 + tid;
    if (i < BDIM * YDIM) {
      float y = yv[i];
      float t = tgt[i];
      s += fmaxf(y, 0.f) - y * t + log1pf(expf(-fabsf(y)));
    }
  }
  red[tid] = s;
  __syncthreads();
  for (int off = 128; off > 0; off >>= 1) {
    if (tid < off) red[tid] += red[tid + off];
    __syncthreads();
  }
  if (tid == 0) part[blockIdx.x] = red[0];
}

__global__ void loss_final(const float* __restrict__ part, float* __restrict__ out) {
  __shared__ float red[128];
  int tid = threadIdx.x;
  red[tid] = (tid < 70) ? part[tid] : 0.f;
  __syncthreads();
  for (int off = 64; off > 0; off >>= 1) {
    if (tid < off) red[tid] += red[tid + off];
    __syncthreads();
  }
  if (tid == 0) out[BDIM * YDIM] = red[0] / (float)(BDIM * YDIM);
}

extern "C" void kernel_launch(void* const* d_in, const int* in_sizes, int n_in,
                              void* d_out, int out_size, void* d_ws, size_t ws_size,
                              hipStream_t stream) {
  const float* x    = (const float*)d_in[0];
  const float* tgt  = (const float*)d_in[1];
  const float* U    = (const float*)d_in[2];
  const float* F    = (const float*)d_in[3];
  const float* bias = (const float*)d_in[4];
  float* out = (float*)d_out;

  unsigned short* xb = (unsigned short*)d_ws;                    // 8*2560*512
  unsigned short* ub = xb + (size_t)BDIM * LPAD * HDIM;          // 8960*512
  unsigned short* fw = ub + (size_t)YPAD * HDIM;                 // 8960*512
  float* part = (float*)(fw + (size_t)YPAD * HDIM);              // 70 floats

  cvt_x_kernel<<<dim3(1280, BDIM), 256, 0, stream>>>(x, xb);
  cvt_w_kernel<<<4480, 256, 0, stream>>>(U, ub);
  cvt_w_kernel<<<4480, 256, 0, stream>>>(F, fw);
  fused_kernel<<<NYT * BDIM, 512, 0, stream>>>(xb, ub, fw, bias, out);
  loss_part<<<70, 256, 0, stream>>>(out, tgt, part);
  loss_final<<<1, 128, 0, stream>>>(part, out);
}

// Round 5
// 530.155 us; speedup vs baseline: 1.9756x; 1.0785x over previous
//
#include <hip/hip_runtime.h>
#include <hip/hip_bf16.h>
#include <cstdint>

#define BDIM 8
#define LDIM 2500
#define HDIM 512
#define YDIM 8921
#define LPAD 2560
#define YPAD 8960
#define NLT 10     // l-tiles of 256
#define NYT 70     // y-tiles of 128 y-rows (256 stacked S/T rows)
#define KSTEPS 8   // K=512 / BK=64

using f32x4  = __attribute__((ext_vector_type(4))) float;
using bf16x8 = __attribute__((ext_vector_type(8))) short;

__device__ __forceinline__ unsigned short f2bf(float f) {
  union { float f; unsigned u; } c; c.f = f;
  unsigned u = c.u;
  unsigned r = (u + 0x7fffu + ((u >> 16) & 1u)) >> 16;  // RNE
  return (unsigned short)r;
}

// ---- convert x [8,2500,512] f32 -> [8,2560,512] bf16 (pad rows zero) ----
__global__ void cvt_x_kernel(const float* __restrict__ x, unsigned short* __restrict__ xb) {
  int e = (blockIdx.x * 256 + threadIdx.x) * 4;
  int b = blockIdx.y;
  int lp = e >> 9;
  int h  = e & 511;
  float4 v = {0.f, 0.f, 0.f, 0.f};
  if (lp < LDIM)
    v = *(const float4*)(x + (((size_t)(b * LDIM + lp)) << 9) + h);
  ushort4 o;
  o.x = f2bf(v.x); o.y = f2bf(v.y); o.z = f2bf(v.z); o.w = f2bf(v.w);
  *(ushort4*)(xb + (((size_t)b * LPAD) << 9) + e) = o;
}

// ---- convert weights [8921,512] f32 -> [8960,512] bf16 (pad rows zero) ----
__global__ void cvt_w_kernel(const float* __restrict__ w, unsigned short* __restrict__ wb) {
  int e = (blockIdx.x * 256 + threadIdx.x) * 4;
  int row = e >> 9;
  int col = e & 511;
  float4 v = {0.f, 0.f, 0.f, 0.f};
  if (row < YDIM)
    v = *(const float4*)(w + ((size_t)row << 9) + col);
  ushort4 o;
  o.x = f2bf(v.x); o.y = f2bf(v.y); o.z = f2bf(v.z); o.w = f2bf(v.w);
  *(ushort4*)(wb + e) = o;
}

// ---- fused 256x256 streamed GEMM tile + per-chunk softmax partials ----
// grid 5600 = b(8, fastest: XCD pin) x (yt*10 + lt).
// Block: 512 thr = 8 waves (2M x 4N), wave-tile 128(stacked) x 64(l).
// K=512 in 8 steps of 64. LDS: dbuf x (A 32KB + B 32KB) = 128KB.
// Rows 128B, XOR-swizzle byte^=(row&7)<<4 (involution, both sides).
// Output: per (b, y, lt) partial {m, e, o} -> combine kernel.
__global__ __launch_bounds__(512, 2) void fused_kernel(
    const unsigned short* __restrict__ xb,
    const unsigned short* __restrict__ ub,
    const unsigned short* __restrict__ fb,
    float* __restrict__ part) {
  __shared__ __align__(16) unsigned char smem[131072];

  const int wid = blockIdx.x;
  const int b   = wid & 7;        // XCD-pinned batch
  const int q   = wid >> 3;       // 0..699
  const int yt  = q / NLT;
  const int lt  = q - yt * NLT;
  const int tid = threadIdx.x;
  const int lane = tid & 63;
  const int wave = tid >> 6;      // 0..7
  const int wm = wave >> 2;       // 0..1 : M half (128 stacked rows)
  const int wn = wave & 3;        // 0..3 : l-column quarter (64)
  const int r16  = lane & 15;
  const int kgrp = lane >> 4;
  const int kg16 = kgrp << 4;
  const int xorR = (r16 & 7) << 4;

  // ---- staging constants: 4 issues x (64 rows x 8 slots of 16B) each for A and B
  const int srow = tid >> 3;      // 0..63
  const int slot = tid & 7;
  const unsigned short* asrc[4];
#pragma unroll
  for (int i = 0; i < 4; ++i) {
    int m = i * 64 + srow;                       // stacked row 0..255
    const unsigned short* Wsrc = (m & 16) ? fb : ub;
    int yrow = yt * 128 + ((m >> 5) << 4) + (m & 15);
    asrc[i] = Wsrc + ((size_t)yrow << 9) + ((slot ^ (m & 7)) << 3);
  }
  const unsigned short* bsrc[4];
#pragma unroll
  for (int i = 0; i < 4; ++i) {
    int r = i * 64 + srow;                       // l-row 0..255
    int lrow = lt * 256 + r;
    bsrc[i] = xb + (((size_t)(b * LPAD + lrow)) << 9) + ((slot ^ (r & 7)) << 3);
  }
  const int ldst = tid * 16;

  // prologue: stage ks=0 into buf0
#pragma unroll
  for (int i = 0; i < 4; ++i) {
    __builtin_amdgcn_global_load_lds(
        (const __attribute__((address_space(1))) void*)(asrc[i]),
        (__attribute__((address_space(3))) void*)(smem + i * 8192 + ldst), 16, 0, 0);
    __builtin_amdgcn_global_load_lds(
        (const __attribute__((address_space(1))) void*)(bsrc[i]),
        (__attribute__((address_space(3))) void*)(smem + 32768 + i * 8192 + ldst), 16, 0, 0);
  }
  __syncthreads();

  f32x4 acc[8][4];
#pragma unroll
  for (int mt = 0; mt < 8; ++mt)
#pragma unroll
    for (int nt = 0; nt < 4; ++nt) acc[mt][nt] = {0.f, 0.f, 0.f, 0.f};

  for (int ks = 0; ks < KSTEPS; ++ks) {
    const int cur = ks & 1;
    // ---- stage next K-step into buf^1 (overlaps with MFMA below) ----
    if (ks < KSTEPS - 1) {
      const int ko = (ks + 1) << 6;
      unsigned char* Ad = smem + (cur ^ 1) * 65536;
#pragma unroll
      for (int i = 0; i < 4; ++i) {
        __builtin_amdgcn_global_load_lds(
            (const __attribute__((address_space(1))) void*)(asrc[i] + ko),
            (__attribute__((address_space(3))) void*)(Ad + i * 8192 + ldst), 16, 0, 0);
        __builtin_amdgcn_global_load_lds(
            (const __attribute__((address_space(1))) void*)(bsrc[i] + ko),
            (__attribute__((address_space(3))) void*)(Ad + 32768 + i * 8192 + ldst), 16, 0, 0);
      }
    }

    // ---- fragments + MFMA on buf[cur] ----
    const unsigned char* Ab = smem + cur * 65536;
    const unsigned char* Bb = Ab + 32768;
#pragma unroll
    for (int kk = 0; kk < 2; ++kk) {
      const int ko = ((kk << 6) + kg16) ^ xorR;
      bf16x8 bfr[4];
#pragma unroll
      for (int nt = 0; nt < 4; ++nt)
        bfr[nt] = *(const bf16x8*)(Bb + (wn * 64 + nt * 16 + r16) * 128 + ko);
#pragma unroll
      for (int mt = 0; mt < 8; ++mt) {
        bf16x8 af = *(const bf16x8*)(Ab + (wm * 128 + mt * 16 + r16) * 128 + ko);
#pragma unroll
        for (int nt = 0; nt < 4; ++nt)
          acc[mt][nt] = __builtin_amdgcn_mfma_f32_16x16x32_bf16(af, bfr[nt], acc[mt][nt], 0, 0, 0);
      }
    }
    __syncthreads();   // drains next-step loads + this step's ds_reads
  }

  // ---- softmax partial over this block's 256 l-columns ----
  // mt even = S, mt odd = T; pair p: y-16-group = wm*4 + p.
  const bool tail = (lt == NLT - 1);
  float* comb = (float*)smem;   // safe: all ds_reads drained by final barrier
#pragma unroll
  for (int p = 0; p < 4; ++p) {
#pragma unroll
    for (int r = 0; r < 4; ++r) {
      float mt_l = fmaxf(fmaxf(acc[2 * p][0][r], acc[2 * p][1][r]),
                         fmaxf(acc[2 * p][2][r], acc[2 * p][3][r]));
      mt_l = fmaxf(mt_l, __shfl_xor(mt_l, 1));
      mt_l = fmaxf(mt_l, __shfl_xor(mt_l, 2));
      mt_l = fmaxf(mt_l, __shfl_xor(mt_l, 4));
      mt_l = fmaxf(mt_l, __shfl_xor(mt_l, 8));
      float e_ = 0.f, o_ = 0.f;
#pragma unroll
      for (int nt = 0; nt < 4; ++nt) {
        float s = acc[2 * p][nt][r];
        float t = acc[2 * p + 1][nt][r];
        float pv = __expf(s - mt_l);
        if (tail) {
          int lg = lt * 256 + wn * 64 + nt * 16 + r16;
          if (lg >= LDIM) pv = 0.f;
        }
        e_ += pv;
        o_ += pv * t;
      }
      e_ += __shfl_xor(e_, 1); o_ += __shfl_xor(o_, 1);
      e_ += __shfl_xor(e_, 2); o_ += __shfl_xor(o_, 2);
      e_ += __shfl_xor(e_, 4); o_ += __shfl_xor(o_, 4);
      e_ += __shfl_xor(e_, 8); o_ += __shfl_xor(o_, 8);
      if (r16 == 0) {
        int y_loc = (wm * 4 + p) * 16 + kgrp * 4 + r;
        float* c = comb + (y_loc * 4 + wn) * 3;
        c[0] = mt_l; c[1] = e_; c[2] = o_;
      }
    }
  }
  __syncthreads();
  if (tid < 128) {
    float* c = comb + tid * 12;
    float M = fmaxf(fmaxf(c[0], c[3]), fmaxf(c[6], c[9]));
    float E = 0.f, O = 0.f;
#pragma unroll
    for (int w = 0; w < 4; ++w) {
      float sw = __expf(c[w * 3] - M);
      E += sw * c[w * 3 + 1];
      O += sw * c[w * 3 + 2];
    }
    size_t gy = (size_t)(b * NYT + yt) * 128 + tid;
    float* pp = part + (gy * NLT + lt) * 3;
    pp[0] = M; pp[1] = E; pp[2] = O;
  }
}

// ---- combine l-chunks: y = O/E + bias ----
__global__ void combine_kernel(const float* __restrict__ part,
                               const float* __restrict__ bias,
                               float* __restrict__ out) {
  int g = blockIdx.x * 256 + threadIdx.x;
  if (g >= BDIM * NYT * 128) return;
  const float* pp = part + (size_t)g * (NLT * 3);
  float M = -1e30f;
#pragma unroll
  for (int i = 0; i < NLT; ++i) M = fmaxf(M, pp[i * 3]);
  float E = 0.f, O = 0.f;
#pragma unroll
  for (int i = 0; i < NLT; ++i) {
    float w = __expf(pp[i * 3] - M);
    E += w * pp[i * 3 + 1];
    O += w * pp[i * 3 + 2];
  }
  int y128 = g & 127;
  int rest = g >> 7;
  int yt = rest % NYT;
  int b  = rest / NYT;
  int y = yt * 128 + y128;
  if (y < YDIM)
    out[b * YDIM + y] = O / E + bias[y];
}

// ---- BCE-with-logits: 70-block partial, then final reduce ----
__global__ void loss_part(const float* __restrict__ yv, const float* __restrict__ tgt,
                          float* __restrict__ partl) {
  __shared__ float red[256];
  int tid = threadIdx.x;
  int base = blockIdx.x * 1024;
  float s = 0.f;
#pragma unroll
  for (int j = 0; j < 4; ++j) {
    int i = base + j * 256 + tid;
    if (i < BDIM * YDIM) {
      float y = yv[i];
      float t = tgt[i];
      s += fmaxf(y, 0.f) - y * t + log1pf(expf(-fabsf(y)));
    }
  }
  red[tid] = s;
  __syncthreads();
  for (int off = 128; off > 0; off >>= 1) {
    if (tid < off) red[tid] += red[tid + off];
    __syncthreads();
  }
  if (tid == 0) partl[blockIdx.x] = red[0];
}

__global__ void loss_final(const float* __restrict__ partl, float* __restrict__ out) {
  __shared__ float red[128];
  int tid = threadIdx.x;
  red[tid] = (tid < 70) ? partl[tid] : 0.f;
  __syncthreads();
  for (int off = 64; off > 0; off >>= 1) {
    if (tid < off) red[tid] += red[tid + off];
    __syncthreads();
  }
  if (tid == 0) out[BDIM * YDIM] = red[0] / (float)(BDIM * YDIM);
}

extern "C" void kernel_launch(void* const* d_in, const int* in_sizes, int n_in,
                              void* d_out, int out_size, void* d_ws, size_t ws_size,
                              hipStream_t stream) {
  const float* x    = (const float*)d_in[0];
  const float* tgt  = (const float*)d_in[1];
  const float* U    = (const float*)d_in[2];
  const float* F    = (const float*)d_in[3];
  const float* bias = (const float*)d_in[4];
  float* out = (float*)d_out;

  unsigned short* xb = (unsigned short*)d_ws;                    // 8*2560*512 ushort
  unsigned short* ub = xb + (size_t)BDIM * LPAD * HDIM;          // 8960*512
  unsigned short* fw = ub + (size_t)YPAD * HDIM;                 // 8960*512
  float* partf = (float*)(fw + (size_t)YPAD * HDIM);             // 8*70*128*10*3 f32
  float* partl = partf + (size_t)BDIM * NYT * 128 * NLT * 3;     // 70 f32

  cvt_x_kernel<<<dim3(1280, BDIM), 256, 0, stream>>>(x, xb);
  cvt_w_kernel<<<4480, 256, 0, stream>>>(U, ub);
  cvt_w_kernel<<<4480, 256, 0, stream>>>(F, fw);
  fused_kernel<<<BDIM * NYT * NLT, 512, 0, stream>>>(xb, ub, fw, partf);
  combine_kernel<<<(BDIM * NYT * 128 + 255) / 256, 256, 0, stream>>>(partf, bias, out);
  loss_part<<<70, 256, 0, stream>>>(out, tgt, partl);
  loss_final<<<1, 128, 0, stream>>>(partl, out);
}

// Round 8
// 492.751 us; speedup vs baseline: 2.1256x; 1.0759x over previous
//
#include <hip/hip_runtime.h>
#include <hip/hip_bf16.h>
#include <cstdint>

#define BDIM 8
#define LDIM 2500
#define HDIM 512
#define YDIM 8921
#define LPAD 2560
#define YPAD 8960
#define NLT 10     // l-tiles of 256
#define NYT 70     // y-tiles of 128 y-rows (256 stacked S/T rows)
#define KSTEPS 8   // K=512 / BK=64

using f32x4  = __attribute__((ext_vector_type(4))) float;
using bf16x8 = __attribute__((ext_vector_type(8))) short;

__device__ __forceinline__ unsigned short f2bf(float f) {
  union { float f; unsigned u; } c; c.f = f;
  unsigned u = c.u;
  unsigned r = (u + 0x7fffu + ((u >> 16) & 1u)) >> 16;  // RNE
  return (unsigned short)r;
}

// ---- convert x [8,2500,512] f32 -> [8,2560,512] bf16 (pad rows zero) ----
__global__ void cvt_x_kernel(const float* __restrict__ x, unsigned short* __restrict__ xb) {
  int e = (blockIdx.x * 256 + threadIdx.x) * 4;
  int b = blockIdx.y;
  int lp = e >> 9;
  int h  = e & 511;
  float4 v = {0.f, 0.f, 0.f, 0.f};
  if (lp < LDIM)
    v = *(const float4*)(x + (((size_t)(b * LDIM + lp)) << 9) + h);
  ushort4 o;
  o.x = f2bf(v.x); o.y = f2bf(v.y); o.z = f2bf(v.z); o.w = f2bf(v.w);
  *(ushort4*)(xb + (((size_t)b * LPAD) << 9) + e) = o;
}

// ---- convert weights [8921,512] f32 -> [8960,512] bf16 (pad rows zero) ----
__global__ void cvt_w_kernel(const float* __restrict__ w, unsigned short* __restrict__ wb) {
  int e = (blockIdx.x * 256 + threadIdx.x) * 4;
  int row = e >> 9;
  int col = e & 511;
  float4 v = {0.f, 0.f, 0.f, 0.f};
  if (row < YDIM)
    v = *(const float4*)(w + ((size_t)row << 9) + col);
  ushort4 o;
  o.x = f2bf(v.x); o.y = f2bf(v.y); o.z = f2bf(v.z); o.w = f2bf(v.w);
  *(ushort4*)(wb + e) = o;
}

// ---------------- asm schedule helpers ----------------
#define BAR() __builtin_amdgcn_s_barrier()
#define LGKM0()                                                     \
  do {                                                              \
    asm volatile("s_waitcnt lgkmcnt(0)" ::: "memory");              \
    __builtin_amdgcn_sched_barrier(0);                              \
  } while (0)
#define VMW(N)                                                      \
  do {                                                              \
    asm volatile("s_waitcnt vmcnt(" #N ")" ::: "memory");           \
    __builtin_amdgcn_sched_barrier(0);                              \
  } while (0)
#define GLD(SD, SRC, DOF)                                           \
  __builtin_amdgcn_global_load_lds(                                 \
      (const __attribute__((address_space(1))) void*)(SRC),         \
      (__attribute__((address_space(3))) void*)((SD) + (DOF)), 16, 0, 0)

#define RDB(P)                                                      \
  do {                                                              \
    _Pragma("unroll")                                               \
    for (int j = 0; j < 4; ++j) {                                   \
      const unsigned char* _r = Bb + ((P) * 64 + j * 16 + r16) * 128; \
      bfr[j][0] = *(const bf16x8*)(_r + koB0);                      \
      bfr[j][1] = *(const bf16x8*)(_r + koB1);                      \
    }                                                               \
  } while (0)

#define MFMAQ(P)                                                    \
  do {                                                              \
    _Pragma("unroll")                                               \
    for (int kk = 0; kk < 2; ++kk) {                                \
      _Pragma("unroll")                                             \
      for (int j = 0; j < 4; ++j) {                                 \
        acc[0][(P) * 4 + j] = __builtin_amdgcn_mfma_f32_16x16x32_bf16( \
            afr[0][kk], bfr[j][kk], acc[0][(P) * 4 + j], 0, 0, 0);  \
        acc[1][(P) * 4 + j] = __builtin_amdgcn_mfma_f32_16x16x32_bf16( \
            afr[1][kk], bfr[j][kk], acc[1][(P) * 4 + j], 0, 0, 0);  \
      }                                                             \
    }                                                               \
  } while (0)

// ---- fused 256x256 tile, 4-phase/K-tile counted-vmcnt schedule ----
// 8 waves = M-strips: wave w owns stacked rows [w*32, w*32+32) x 256 l.
// LDS: dbuf x (A 32KB + B 32KB). Staging order/tile: B-h0, A(own strip), B-h1.
// Waits: vmcnt(2) at tile boundary, vmcnt(4) mid-tile (vmcnt(0) last tile).
__global__ __launch_bounds__(512, 2) void fused_kernel(
    const unsigned short* __restrict__ xb,
    const unsigned short* __restrict__ ub,
    const unsigned short* __restrict__ fb,
    float* __restrict__ part) {
  __shared__ __align__(16) unsigned char smem[131072];

  const int wid = blockIdx.x;
  const int b   = wid & 7;        // XCD-pinned batch
  const int q   = wid >> 3;
  const int yt  = q / NLT;
  const int lt  = q - yt * NLT;
  const int tid = threadIdx.x;
  const int lane = tid & 63;
  const int w    = tid >> 6;      // wave 0..7 : M-strip
  const int r16  = lane & 15;
  const int kgrp = lane >> 4;
  const int kg16 = kgrp << 4;
  const int xorR = (r16 & 7) << 4;
  const int koB0 = kg16 ^ xorR;
  const int koB1 = (64 + kg16) ^ xorR;
  const int w32  = w * 32;
  const int lane16 = lane * 16;
  const int colofs = ((lane & 7) ^ (lane >> 3)) << 3;   // pre-swizzled src slot

  // ---- staging sources (elements) + LDS dest offsets (bytes) ----
  const unsigned short* asp[4]; int adst[4];
#pragma unroll
  for (int i = 0; i < 4; ++i) {
    int m = w32 + i * 8 + (lane >> 3);                  // stacked row
    const unsigned short* Wsrc = (m & 16) ? fb : ub;
    int yrow = yt * 128 + ((m >> 5) << 4) + (m & 15);
    asp[i]  = Wsrc + ((size_t)yrow << 9) + colofs;
    adst[i] = w32 * 128 + i * 1024 + lane16;
  }
  const unsigned short* bp[4]; int bdst[4];
#pragma unroll
  for (int i = 0; i < 2; ++i) {
    int lr0 = w * 16 + i * 8 + (lane >> 3);             // B-h0 row
    bp[i]      = xb + (((size_t)(b * LPAD + lt * 256 + lr0)) << 9) + colofs;
    bdst[i]    = 32768 + (w * 16 + i * 8) * 128 + lane16;
    int lr1 = 128 + w * 16 + i * 8 + (lane >> 3);       // B-h1 row
    bp[2 + i]  = xb + (((size_t)(b * LPAD + lt * 256 + lr1)) << 9) + colofs;
    bdst[2 + i] = 32768 + (128 + w * 16 + i * 8) * 128 + lane16;
  }

  // ---- prologue: stage tile 0 (order: B-h0, A, B-h1) ----
  {
    unsigned char* sd = (unsigned char*)smem;
    GLD(sd, bp[0], bdst[0]); GLD(sd, bp[1], bdst[1]);
#pragma unroll
    for (int i = 0; i < 4; ++i) GLD(sd, asp[i], adst[i]);
    GLD(sd, bp[2], bdst[2]); GLD(sd, bp[3], bdst[3]);
  }
  VMW(2);   // B-h0 + A landed; B-h1 still in flight
  BAR();

  f32x4 acc[2][16];
#pragma unroll
  for (int mt = 0; mt < 2; ++mt)
#pragma unroll
    for (int nt = 0; nt < 16; ++nt) acc[mt][nt] = {0.f, 0.f, 0.f, 0.f};

  for (int ks = 0; ks < KSTEPS; ++ks) {
    const unsigned char* Ab = (const unsigned char*)smem + ((ks & 1) << 16);
    const unsigned char* Bb = Ab + 32768;
    unsigned char* sd = (unsigned char*)smem + (((ks & 1) ^ 1) << 16);
    const int ko = (ks + 1) << 6;          // next tile's K offset (elems)
    const bool st = (ks < KSTEPS - 1);
    bf16x8 afr[2][2];
    bf16x8 bfr[4][2];

    // ---- phase 0: B rows 0-63 + A frags; stage next B-h0 ----
    RDB(0);
#pragma unroll
    for (int mt = 0; mt < 2; ++mt) {
      const unsigned char* _a = Ab + (w32 + mt * 16 + r16) * 128;
      afr[mt][0] = *(const bf16x8*)(_a + koB0);
      afr[mt][1] = *(const bf16x8*)(_a + koB1);
    }
    if (st) { GLD(sd, bp[0] + ko, bdst[0]); GLD(sd, bp[1] + ko, bdst[1]); }
    BAR(); LGKM0();
    __builtin_amdgcn_s_setprio(1); MFMAQ(0); __builtin_amdgcn_s_setprio(0);
    BAR();

    // ---- phase 1: B rows 64-127; stage next A01; mid vmcnt ----
    RDB(1);
    if (st) { GLD(sd, asp[0] + ko, adst[0]); GLD(sd, asp[1] + ko, adst[1]); }
    BAR(); LGKM0();
    __builtin_amdgcn_s_setprio(1); MFMAQ(1); __builtin_amdgcn_s_setprio(0);
    if (st) { VMW(4); } else { VMW(0); }   // this tile's B-h1 landed
    BAR();

    // ---- phase 2: B rows 128-191; stage next A23 ----
    RDB(2);
    if (st) { GLD(sd, asp[2] + ko, adst[2]); GLD(sd, asp[3] + ko, adst[3]); }
    BAR(); LGKM0();
    __builtin_amdgcn_s_setprio(1); MFMAQ(2); __builtin_amdgcn_s_setprio(0);
    BAR();

    // ---- phase 3: B rows 192-255; stage next B-h1; boundary vmcnt ----
    RDB(3);
    if (st) { GLD(sd, bp[2] + ko, bdst[2]); GLD(sd, bp[3] + ko, bdst[3]); }
    BAR(); LGKM0();
    __builtin_amdgcn_s_setprio(1); MFMAQ(3); __builtin_amdgcn_s_setprio(0);
    VMW(2);                                // next tile's B-h0 + A landed
    BAR();
  }

  // ---- wave-local softmax partial: 16 y-rows x 256 l per wave ----
  const bool tail = (lt == NLT - 1);
#pragma unroll
  for (int r = 0; r < 4; ++r) {
    float mv = -1e30f;
#pragma unroll
    for (int nt = 0; nt < 16; ++nt) mv = fmaxf(mv, acc[0][nt][r]);
    mv = fmaxf(mv, __shfl_xor(mv, 1));
    mv = fmaxf(mv, __shfl_xor(mv, 2));
    mv = fmaxf(mv, __shfl_xor(mv, 4));
    mv = fmaxf(mv, __shfl_xor(mv, 8));
    float e_ = 0.f, o_ = 0.f;
#pragma unroll
    for (int nt = 0; nt < 16; ++nt) {
      float s = acc[0][nt][r];
      float t = acc[1][nt][r];
      float pv = __expf(s - mv);
      if (tail) {
        int lg = lt * 256 + nt * 16 + r16;
        if (lg >= LDIM) pv = 0.f;
      }
      e_ += pv;
      o_ += pv * t;
    }
    e_ += __shfl_xor(e_, 1); o_ += __shfl_xor(o_, 1);
    e_ += __shfl_xor(e_, 2); o_ += __shfl_xor(o_, 2);
    e_ += __shfl_xor(e_, 4); o_ += __shfl_xor(o_, 4);
    e_ += __shfl_xor(e_, 8); o_ += __shfl_xor(o_, 8);
    if (r16 == 0) {
      int y_loc = w * 16 + kgrp * 4 + r;
      size_t gy = (size_t)(b * NYT + yt) * 128 + y_loc;
      float* pp = part + (gy * NLT + lt) * 3;
      pp[0] = mv; pp[1] = e_; pp[2] = o_;
    }
  }
}

// ---- combine l-chunks: y = O/E + bias ----
__global__ void combine_kernel(const float* __restrict__ part,
                               const float* __restrict__ bias,
                               float* __restrict__ out) {
  int g = blockIdx.x * 256 + threadIdx.x;
  if (g >= BDIM * NYT * 128) return;
  const float* pp = part + (size_t)g * (NLT * 3);
  float M = -1e30f;
#pragma unroll
  for (int i = 0; i < NLT; ++i) M = fmaxf(M, pp[i * 3]);
  float E = 0.f, O = 0.f;
#pragma unroll
  for (int i = 0; i < NLT; ++i) {
    float w = __expf(pp[i * 3] - M);
    E += w * pp[i * 3 + 1];
    O += w * pp[i * 3 + 2];
  }
  int y128 = g & 127;
  int rest = g >> 7;
  int yt = rest % NYT;
  int b  = rest / NYT;
  int y = yt * 128 + y128;
  if (y < YDIM)
    out[b * YDIM + y] = O / E + bias[y];
}

// ---- BCE-with-logits: 70-block partial, then final reduce ----
__global__ void loss_part(const float* __restrict__ yv, const float* __restrict__ tgt,
                          float* __restrict__ partl) {
  __shared__ float red[256];
  int tid = threadIdx.x;
  int base = blockIdx.x * 1024;
  float s = 0.f;
#pragma unroll
  for (int j = 0; j < 4; ++j) {
    int i = base + j * 256 + tid;
    if (i < BDIM * YDIM) {
      float y = yv[i];
      float t = tgt[i];
      s += fmaxf(y, 0.f) - y * t + log1pf(expf(-fabsf(y)));
    }
  }
  red[tid] = s;
  __syncthreads();
  for (int off = 128; off > 0; off >>= 1) {
    if (tid < off) red[tid] += red[tid + off];
    __syncthreads();
  }
  if (tid == 0) partl[blockIdx.x] = red[0];
}

__global__ void loss_final(const float* __restrict__ partl, float* __restrict__ out) {
  __shared__ float red[128];
  int tid = threadIdx.x;
  red[tid] = (tid < 70) ? partl[tid] : 0.f;
  __syncthreads();
  for (int off = 64; off > 0; off >>= 1) {
    if (tid < off) red[tid] += red[tid + off];
    __syncthreads();
  }
  if (tid == 0) out[BDIM * YDIM] = red[0] / (float)(BDIM * YDIM);
}

extern "C" void kernel_launch(void* const* d_in, const int* in_sizes, int n_in,
                              void* d_out, int out_size, void* d_ws, size_t ws_size,
                              hipStream_t stream) {
  const float* x    = (const float*)d_in[0];
  const float* tgt  = (const float*)d_in[1];
  const float* U    = (const float*)d_in[2];
  const float* F    = (const float*)d_in[3];
  const float* bias = (const float*)d_in[4];
  float* out = (float*)d_out;

  unsigned short* xb = (unsigned short*)d_ws;                    // 8*2560*512 ushort
  unsigned short* ub = xb + (size_t)BDIM * LPAD * HDIM;          // 8960*512
  unsigned short* fw = ub + (size_t)YPAD * HDIM;                 // 8960*512
  float* partf = (float*)(fw + (size_t)YPAD * HDIM);             // 8*70*128*10*3 f32
  float* partl = partf + (size_t)BDIM * NYT * 128 * NLT * 3;     // 70 f32

  cvt_x_kernel<<<dim3(1280, BDIM), 256, 0, stream>>>(x, xb);
  cvt_w_kernel<<<4480, 256, 0, stream>>>(U, ub);
  cvt_w_kernel<<<4480, 256, 0, stream>>>(F, fw);
  fused_kernel<<<BDIM * NYT * NLT, 512, 0, stream>>>(xb, ub, fw, partf);
  combine_kernel<<<(BDIM * NYT * 128 + 255) / 256, 256, 0, stream>>>(partf, bias, out);
  loss_part<<<70, 256, 0, stream>>>(out, tgt, partl);
  loss_final<<<1, 128, 0, stream>>>(partl, out);
}